// Round 2
// baseline (832.299 us; speedup 1.0000x reference)
//
#include <hip/hip_runtime.h>
#include <hip/hip_bf16.h>
#include <stdint.h>

#define BB 2
#define SS 2048
#define HH 1024
#define NHEAD 16
#define NKVH 8
#define DD 128
#define MM (BB*SS)   // 4096 rows

typedef __bf16 bf16_t;
typedef __bf16 bf16x8 __attribute__((ext_vector_type(8)));
typedef __bf16 bf16x4 __attribute__((ext_vector_type(4)));
typedef float  f32x4  __attribute__((ext_vector_type(4)));

// ---------------- fp32 -> bf16 convert (vectorized, grid-stride) ----------------
__global__ __launch_bounds__(256) void k_cvt(const float* __restrict__ in,
                                             bf16_t* __restrict__ out, int n4) {
  int i = blockIdx.x * 256 + threadIdx.x;
  const int stride = gridDim.x * 256;
  for (; i < n4; i += stride) {
    float4 v = reinterpret_cast<const float4*>(in)[i];
    bf16x4 o;
    o[0] = (bf16_t)v.x; o[1] = (bf16_t)v.y; o[2] = (bf16_t)v.z; o[3] = (bf16_t)v.w;
    reinterpret_cast<bf16x4*>(out)[i] = o;
  }
}

// ---------------- GEMM: C[M,N] = A[M,K] * B[N,K]^T  (bf16 in, CT out) ----------------
// 128x128 tile, BK=64, 4 waves (2x2), each wave 64x64 via 4x4 16x16x32 MFMA frags.
template <typename CT>
__global__ __launch_bounds__(256, 2) void k_gemm_bt(
    const bf16_t* __restrict__ A, const bf16_t* __restrict__ Bm,
    CT* __restrict__ C, int M, int N, int K) {
  __shared__ bf16_t As[128 * 72];   // pad 64->72: frag reads ~2-way conflict
  __shared__ bf16_t Bs[128 * 72];
  const int t = threadIdx.x;
  const int lane = t & 63, wave = t >> 6;
  const int c = lane & 15, g = lane >> 4;
  const int wm = wave >> 1, wn = wave & 1;
  const long m0 = (long)blockIdx.y * 128;
  const long n0 = (long)blockIdx.x * 128;
  const int srow = t >> 3, sc8 = t & 7;   // 32 rows x 8 chunks of 8 = 64 cols (BK)

  const bf16_t* Ag = A + (m0 + srow) * K + sc8 * 8;
  const bf16_t* Bg = Bm + (n0 + srow) * K + sc8 * 8;

  f32x4 acc[4][4] = {};
  uint4 ra[4], rb[4];
#pragma unroll
  for (int i = 0; i < 4; ++i) {
    ra[i] = *reinterpret_cast<const uint4*>(Ag + (long)i * 32 * K);
    rb[i] = *reinterpret_cast<const uint4*>(Bg + (long)i * 32 * K);
  }
  const int nk = K >> 6;
  for (int kt = 0; kt < nk; ++kt) {
    __syncthreads();
#pragma unroll
    for (int i = 0; i < 4; ++i) {
      *reinterpret_cast<uint4*>(&As[(srow + i * 32) * 72 + sc8 * 8]) = ra[i];
      *reinterpret_cast<uint4*>(&Bs[(srow + i * 32) * 72 + sc8 * 8]) = rb[i];
    }
    __syncthreads();
    if (kt + 1 < nk) {
      const long off = (long)(kt + 1) * 64;
#pragma unroll
      for (int i = 0; i < 4; ++i) {
        ra[i] = *reinterpret_cast<const uint4*>(Ag + (long)i * 32 * K + off);
        rb[i] = *reinterpret_cast<const uint4*>(Bg + (long)i * 32 * K + off);
      }
    }
#pragma unroll
    for (int kk = 0; kk < 2; ++kk) {
      bf16x8 af[4], bfr[4];
#pragma unroll
      for (int mi = 0; mi < 4; ++mi)
        af[mi] = *reinterpret_cast<const bf16x8*>(
            &As[(wm * 64 + mi * 16 + c) * 72 + kk * 32 + g * 8]);
#pragma unroll
      for (int ni = 0; ni < 4; ++ni)
        bfr[ni] = *reinterpret_cast<const bf16x8*>(
            &Bs[(wn * 64 + ni * 16 + c) * 72 + kk * 32 + g * 8]);
#pragma unroll
      for (int mi = 0; mi < 4; ++mi)
#pragma unroll
        for (int ni = 0; ni < 4; ++ni)
          acc[mi][ni] = __builtin_amdgcn_mfma_f32_16x16x32_bf16(
              af[mi], bfr[ni], acc[mi][ni], 0, 0, 0);
    }
  }
  // C/D layout: col = lane&15, row = (lane>>4)*4 + r
#pragma unroll
  for (int mi = 0; mi < 4; ++mi)
#pragma unroll
    for (int ni = 0; ni < 4; ++ni)
#pragma unroll
      for (int r = 0; r < 4; ++r) {
        long m = m0 + wm * 64 + mi * 16 + 4 * g + r;
        long n = n0 + wn * 64 + ni * 16 + c;
        C[m * N + n] = (CT)acc[mi][ni][r];
      }
}

// ---------------- fused RMSNorm + RoPE + [B,S,h,D]->[B,h,S,D] transpose ----------------
// one wave per (b,s,head); lane l holds d=l and d=l+64 (rotate_half is lane-local)
template <int DO_NR>
__global__ __launch_bounds__(256) void k_nr(
    const bf16_t* __restrict__ raw, bf16_t* __restrict__ outp,
    const float* __restrict__ w, const float* __restrict__ cosb,
    const float* __restrict__ sinb, int nheads) {
  const int wid = (blockIdx.x * 256 + threadIdx.x) >> 6;
  const int lane = threadIdx.x & 63;
  const int h = wid % nheads;
  const int bs = wid / nheads;           // b*S + s
  const int b = bs / SS, s = bs - b * SS;
  const bf16_t* rp = raw + ((long)bs * nheads + h) * DD;
  float x0 = (float)rp[lane];
  float x1 = (float)rp[lane + 64];
  bf16_t o0, o1;
  if (DO_NR) {
    float ssq = x0 * x0 + x1 * x1;
#pragma unroll
    for (int m = 1; m < 64; m <<= 1) ssq += __shfl_xor(ssq, m);
    const float rs = rsqrtf(ssq * (1.0f / DD) + 1e-6f);
    const float xn0 = x0 * rs * w[lane];
    const float xn1 = x1 * rs * w[lane + 64];
    const float cc = cosb[(long)bs * DD + lane];   // cos[d+64]==cos[d]
    const float sn = sinb[(long)bs * DD + lane];
    o0 = (bf16_t)(xn0 * cc - xn1 * sn);
    o1 = (bf16_t)(xn1 * cc + xn0 * sn);
  } else {
    o0 = (bf16_t)x0; o1 = (bf16_t)x1;
  }
  bf16_t* op = outp + (((long)b * nheads + h) * SS + s) * DD;
  op[lane] = o0;
  op[lane + 64] = o1;
}

// ---------------- causal GQA flash attention ----------------
// block: 4 waves, each wave owns 16 q-rows; KVBLK=32 staged in LDS (V transposed).
// Swapped QK^T (mfma(K,Q) -> S^T) so row-softmax is in-lane + 2 shuffles.
__global__ __launch_bounds__(256, 2) void k_attn(
    const bf16_t* __restrict__ Qh, const bf16_t* __restrict__ Kh,
    const bf16_t* __restrict__ Vh, bf16_t* __restrict__ AO) {
  __shared__ bf16_t Ks[32 * 144];      // [key][d], pad 128->144
  __shared__ bf16_t Vs[128 * 32];      // V^T: [d][key]
  __shared__ bf16_t Pq[4 * 16 * 32];   // per-wave P: [q][key]
  const int t = threadIdx.x;
  const int lane = t & 63, wave = t >> 6;
  const int c = lane & 15, g = lane >> 4;
  const int qt = blockIdx.x, h = blockIdx.y, b = blockIdx.z;
  const int kvh = h >> 1;                       // GQA: n_rep = 2
  const int qbase = qt * 64 + wave * 16;
  const int qg = qbase + c;
  const bf16_t* qp = Qh + (((long)b * NHEAD + h) * SS + qg) * DD;
  bf16x8 qf[4];
#pragma unroll
  for (int kb = 0; kb < 4; ++kb)
    qf[kb] = *reinterpret_cast<const bf16x8*>(qp + kb * 32 + g * 8);
  const bf16_t* kp = Kh + ((long)b * NKVH + kvh) * SS * DD;
  const bf16_t* vp = Vh + ((long)b * NKVH + kvh) * SS * DD;
  f32x4 o[8] = {};
  float mrow = -1e30f, lrow = 0.0f;
  // staging: 16 rows x 16 chunks of 8 = full [32][128] in two row-passes
  const int srow2 = t >> 4, sc16 = t & 15;
  const int kv_end = qt * 64 + 64;
  const float scale = 0.08838834764831845f;     // 1/sqrt(128)

  for (int kv0 = 0; kv0 < kv_end; kv0 += 32) {
    __syncthreads();
#pragma unroll
    for (int rr = 0; rr < 2; ++rr) {
      const int row = srow2 + rr * 16;
      // stage K tile [32][128] (row-contiguous)
      *reinterpret_cast<uint4*>(&Ks[row * 144 + sc16 * 8]) =
          *reinterpret_cast<const uint4*>(kp + (long)(kv0 + row) * DD + sc16 * 8);
      // stage V transposed -> Vs[d][key]
      uint4 vv = *reinterpret_cast<const uint4*>(vp + (long)(kv0 + row) * DD + sc16 * 8);
      unsigned int vw[4] = {vv.x, vv.y, vv.z, vv.w};
      unsigned short* Vsu = reinterpret_cast<unsigned short*>(Vs);
#pragma unroll
      for (int j = 0; j < 4; ++j) {
        Vsu[(sc16 * 8 + 2 * j) * 32 + row]     = (unsigned short)(vw[j] & 0xffffu);
        Vsu[(sc16 * 8 + 2 * j + 1) * 32 + row] = (unsigned short)(vw[j] >> 16);
      }
    }
    __syncthreads();

    // S^T = K · Q^T : lane holds S^T[key=t2*16+4g+r][q=c]
    f32x4 s0 = {0.f, 0.f, 0.f, 0.f}, s1 = {0.f, 0.f, 0.f, 0.f};
#pragma unroll
    for (int kb = 0; kb < 4; ++kb) {
      bf16x8 k0 = *reinterpret_cast<const bf16x8*>(&Ks[c * 144 + kb * 32 + g * 8]);
      bf16x8 k1 = *reinterpret_cast<const bf16x8*>(&Ks[(16 + c) * 144 + kb * 32 + g * 8]);
      s0 = __builtin_amdgcn_mfma_f32_16x16x32_bf16(k0, qf[kb], s0, 0, 0, 0);
      s1 = __builtin_amdgcn_mfma_f32_16x16x32_bf16(k1, qf[kb], s1, 0, 0, 0);
    }
    float sv[8];
#pragma unroll
    for (int r = 0; r < 4; ++r) { sv[r] = s0[r]; sv[4 + r] = s1[r]; }
#pragma unroll
    for (int i = 0; i < 8; ++i) {
      int key = kv0 + (i >> 2) * 16 + 4 * g + (i & 3);
      sv[i] = (key <= qg) ? sv[i] * scale : -1e30f;
    }
    float vm = sv[0];
#pragma unroll
    for (int i = 1; i < 8; ++i) vm = fmaxf(vm, sv[i]);
    vm = fmaxf(vm, __shfl_xor(vm, 16));
    vm = fmaxf(vm, __shfl_xor(vm, 32));
    const float mnew = fmaxf(mrow, vm);
    const float alpha = __expf(mrow - mnew);
    float p[8], ps = 0.0f;
#pragma unroll
    for (int i = 0; i < 8; ++i) { p[i] = __expf(sv[i] - mnew); ps += p[i]; }
    ps += __shfl_xor(ps, 16);
    ps += __shfl_xor(ps, 32);
    lrow = lrow * alpha + ps;
    mrow = mnew;
#pragma unroll
    for (int dt = 0; dt < 8; ++dt) o[dt] = o[dt] * alpha;

    // P (bf16) -> per-wave LDS [q][key], then read back as B-frag of PV
    bf16x4 pk0, pk1;
#pragma unroll
    for (int r = 0; r < 4; ++r) { pk0[r] = (bf16_t)p[r]; pk1[r] = (bf16_t)p[4 + r]; }
    *reinterpret_cast<bf16x4*>(&Pq[(wave * 16 + c) * 32 + 4 * g]) = pk0;
    *reinterpret_cast<bf16x4*>(&Pq[(wave * 16 + c) * 32 + 16 + 4 * g]) = pk1;
    bf16x8 pf = *reinterpret_cast<const bf16x8*>(&Pq[(wave * 16 + c) * 32 + g * 8]);
    // O^T += V^T · P^T : lane holds O^T[d=dt*16+4g+r][q=c]
#pragma unroll
    for (int dt = 0; dt < 8; ++dt) {
      bf16x8 vf = *reinterpret_cast<const bf16x8*>(&Vs[(dt * 16 + c) * 32 + g * 8]);
      o[dt] = __builtin_amdgcn_mfma_f32_16x16x32_bf16(vf, pf, o[dt], 0, 0, 0);
    }
  }
  const float linv = 1.0f / lrow;
  bf16_t* aop = AO + ((long)(b * SS) + qg) * (NHEAD * DD) + h * DD;
#pragma unroll
  for (int dt = 0; dt < 8; ++dt) {
    bf16x4 ov;
#pragma unroll
    for (int r = 0; r < 4; ++r) ov[r] = (bf16_t)(o[dt][r] * linv);
    *reinterpret_cast<bf16x4*>(aop + dt * 16 + 4 * g) = ov;
  }
}

// ---------------- launch ----------------
extern "C" void kernel_launch(void* const* d_in, const int* in_sizes, int n_in,
                              void* d_out, int out_size, void* d_ws, size_t ws_size,
                              hipStream_t stream) {
  const float* hidden = (const float*)d_in[0];
  const float* cosb   = (const float*)d_in[1];
  const float* sinb   = (const float*)d_in[2];
  const float* Wq     = (const float*)d_in[3];
  const float* Wk     = (const float*)d_in[4];
  const float* Wv     = (const float*)d_in[5];
  const float* Wo     = (const float*)d_in[6];
  const float* qnw    = (const float*)d_in[7];
  const float* knw    = (const float*)d_in[8];
  float* outp = (float*)d_out;
  char* ws = (char*)d_ws;
  const size_t MB = 1024 * 1024;
  bf16_t* hbf  = (bf16_t*)(ws + 0);        //  8 MB  hidden bf16 [4096][1024]
  bf16_t* wqb  = (bf16_t*)(ws + 8 * MB);   //  4 MB
  bf16_t* wkb  = (bf16_t*)(ws + 12 * MB);  //  2 MB
  bf16_t* wvb  = (bf16_t*)(ws + 14 * MB);  //  2 MB
  bf16_t* wob  = (bf16_t*)(ws + 16 * MB);  //  4 MB
  bf16_t* qraw = (bf16_t*)(ws + 20 * MB);  // 16 MB [4096][2048]; reused as ao later
  bf16_t* kraw = (bf16_t*)(ws + 36 * MB);  //  8 MB
  bf16_t* vraw = (bf16_t*)(ws + 44 * MB);  //  8 MB
  bf16_t* qn   = (bf16_t*)(ws + 52 * MB);  // 16 MB [B,NH,S,D]
  bf16_t* kn   = (bf16_t*)(ws + 68 * MB);  //  8 MB [B,NKV,S,D]
  bf16_t* vn   = (bf16_t*)(ws + 76 * MB);  //  8 MB [B,NKV,S,D]   (total 84 MB)
  bf16_t* ao   = qraw;

  k_cvt<<<2048, 256, 0, stream>>>(hidden, hbf, MM * HH / 4);
  k_cvt<<<1024, 256, 0, stream>>>(Wq, wqb, NHEAD * DD * HH / 4);
  k_cvt<<<512, 256, 0, stream>>>(Wk, wkb, NKVH * DD * HH / 4);
  k_cvt<<<512, 256, 0, stream>>>(Wv, wvb, NKVH * DD * HH / 4);
  k_cvt<<<1024, 256, 0, stream>>>(Wo, wob, HH * NHEAD * DD / 4);

  k_gemm_bt<bf16_t><<<dim3(16, 32), 256, 0, stream>>>(hbf, wqb, qraw, MM, 2048, 1024);
  k_gemm_bt<bf16_t><<<dim3(8, 32), 256, 0, stream>>>(hbf, wkb, kraw, MM, 1024, 1024);
  k_gemm_bt<bf16_t><<<dim3(8, 32), 256, 0, stream>>>(hbf, wvb, vraw, MM, 1024, 1024);

  k_nr<1><<<MM * NHEAD / 4, 256, 0, stream>>>(qraw, qn, qnw, cosb, sinb, NHEAD);
  k_nr<1><<<MM * NKVH / 4, 256, 0, stream>>>(kraw, kn, knw, cosb, sinb, NKVH);
  k_nr<0><<<MM * NKVH / 4, 256, 0, stream>>>(vraw, vn, knw, cosb, sinb, NKVH);

  k_attn<<<dim3(SS / 64, NHEAD, BB), 256, 0, stream>>>(qn, kn, vn, ao);

  k_gemm_bt<float><<<dim3(8, 32), 256, 0, stream>>>(ao, wob, outp, MM, 1024, 2048);
}

// Round 6
// 576.819 us; speedup vs baseline: 1.4429x; 1.4429x over previous
//
#include <hip/hip_runtime.h>
#include <hip/hip_bf16.h>
#include <stdint.h>

#define BB 2
#define SS 2048
#define HH 1024
#define NHEAD 16
#define NKVH 8
#define DD 128
#define MM (BB*SS)   // 4096 rows

typedef __bf16 bf16_t;
typedef __bf16 bf16x8 __attribute__((ext_vector_type(8)));
typedef __bf16 bf16x4 __attribute__((ext_vector_type(4)));
typedef float  f32x4  __attribute__((ext_vector_type(4)));

// ---------------- fp32 -> bf16 convert (vectorized, grid-stride) ----------------
__global__ __launch_bounds__(256) void k_cvt(const float* __restrict__ in,
                                             bf16_t* __restrict__ out, int n4) {
  int i = blockIdx.x * 256 + threadIdx.x;
  const int stride = gridDim.x * 256;
  for (; i < n4; i += stride) {
    float4 v = reinterpret_cast<const float4*>(in)[i];
    bf16x4 o;
    o[0] = (bf16_t)v.x; o[1] = (bf16_t)v.y; o[2] = (bf16_t)v.z; o[3] = (bf16_t)v.w;
    reinterpret_cast<bf16x4*>(out)[i] = o;
  }
}

// ---------------- GEMM: C[M,N] = A[M,K] * B[N,K]^T  (bf16 in, CT out) ----------------
template <typename CT>
__global__ __launch_bounds__(256, 2) void k_gemm_bt(
    const bf16_t* __restrict__ A, const bf16_t* __restrict__ Bm,
    CT* __restrict__ C, int M, int N, int K) {
  __shared__ bf16_t As[128 * 72];
  __shared__ bf16_t Bs[128 * 72];
  const int t = threadIdx.x;
  const int lane = t & 63, wave = t >> 6;
  const int c = lane & 15, g = lane >> 4;
  const int wm = wave >> 1, wn = wave & 1;
  const long m0 = (long)blockIdx.y * 128;
  const long n0 = (long)blockIdx.x * 128;
  const int srow = t >> 3, sc8 = t & 7;

  const bf16_t* Ag = A + (m0 + srow) * K + sc8 * 8;
  const bf16_t* Bg = Bm + (n0 + srow) * K + sc8 * 8;

  f32x4 acc[4][4] = {};
  uint4 ra[4], rb[4];
#pragma unroll
  for (int i = 0; i < 4; ++i) {
    ra[i] = *reinterpret_cast<const uint4*>(Ag + (long)i * 32 * K);
    rb[i] = *reinterpret_cast<const uint4*>(Bg + (long)i * 32 * K);
  }
  const int nk = K >> 6;
  for (int kt = 0; kt < nk; ++kt) {
    __syncthreads();
#pragma unroll
    for (int i = 0; i < 4; ++i) {
      *reinterpret_cast<uint4*>(&As[(srow + i * 32) * 72 + sc8 * 8]) = ra[i];
      *reinterpret_cast<uint4*>(&Bs[(srow + i * 32) * 72 + sc8 * 8]) = rb[i];
    }
    __syncthreads();
    if (kt + 1 < nk) {
      const long off = (long)(kt + 1) * 64;
#pragma unroll
      for (int i = 0; i < 4; ++i) {
        ra[i] = *reinterpret_cast<const uint4*>(Ag + (long)i * 32 * K + off);
        rb[i] = *reinterpret_cast<const uint4*>(Bg + (long)i * 32 * K + off);
      }
    }
#pragma unroll
    for (int kk = 0; kk < 2; ++kk) {
      bf16x8 af[4], bfr[4];
#pragma unroll
      for (int mi = 0; mi < 4; ++mi)
        af[mi] = *reinterpret_cast<const bf16x8*>(
            &As[(wm * 64 + mi * 16 + c) * 72 + kk * 32 + g * 8]);
#pragma unroll
      for (int ni = 0; ni < 4; ++ni)
        bfr[ni] = *reinterpret_cast<const bf16x8*>(
            &Bs[(wn * 64 + ni * 16 + c) * 72 + kk * 32 + g * 8]);
#pragma unroll
      for (int mi = 0; mi < 4; ++mi)
#pragma unroll
        for (int ni = 0; ni < 4; ++ni)
          acc[mi][ni] = __builtin_amdgcn_mfma_f32_16x16x32_bf16(
              af[mi], bfr[ni], acc[mi][ni], 0, 0, 0);
    }
  }
#pragma unroll
  for (int mi = 0; mi < 4; ++mi)
#pragma unroll
    for (int ni = 0; ni < 4; ++ni)
#pragma unroll
      for (int r = 0; r < 4; ++r) {
        long m = m0 + wm * 64 + mi * 16 + 4 * g + r;
        long n = n0 + wn * 64 + ni * 16 + c;
        C[m * N + n] = (CT)acc[mi][ni][r];
      }
}

// ---------------- fused RMSNorm + RoPE + [B,S,h,D]->[B,h,S,D] transpose ----------------
template <int DO_NR>
__global__ __launch_bounds__(256) void k_nr(
    const bf16_t* __restrict__ raw, bf16_t* __restrict__ outp,
    const float* __restrict__ w, const float* __restrict__ cosb,
    const float* __restrict__ sinb, int nheads) {
  const int wid = (blockIdx.x * 256 + threadIdx.x) >> 6;
  const int lane = threadIdx.x & 63;
  const int h = wid % nheads;
  const int bs = wid / nheads;           // b*S + s
  const int b = bs / SS, s = bs - b * SS;
  const bf16_t* rp = raw + ((long)bs * nheads + h) * DD;
  float x0 = (float)rp[lane];
  float x1 = (float)rp[lane + 64];
  bf16_t o0, o1;
  if (DO_NR) {
    float ssq = x0 * x0 + x1 * x1;
#pragma unroll
    for (int m = 1; m < 64; m <<= 1) ssq += __shfl_xor(ssq, m);
    const float rs = rsqrtf(ssq * (1.0f / DD) + 1e-6f);
    const float xn0 = x0 * rs * w[lane];
    const float xn1 = x1 * rs * w[lane + 64];
    const float cc = cosb[(long)bs * DD + lane];
    const float sn = sinb[(long)bs * DD + lane];
    o0 = (bf16_t)(xn0 * cc - xn1 * sn);
    o1 = (bf16_t)(xn1 * cc + xn0 * sn);
  } else {
    o0 = (bf16_t)x0; o1 = (bf16_t)x1;
  }
  bf16_t* op = outp + (((long)b * nheads + h) * SS + s) * DD;
  op[lane] = o0;
  op[lane + 64] = o1;
}

// ---------------- causal GQA flash attention v3 ----------------
// 4 waves, each owns 32 q rows (block Q-tile 128); KVBLK=64.
// K: row-major XOR-swizzled LDS (v2, audited). V: V^T [128][66] via verified
// v1-style ushort scatter (pad 64->66 spreads store banks; reads via 4x b32).
// P^T: per-wave XOR-swizzled LDS (v2, audited).
__global__ __launch_bounds__(256, 2) void k_attn(
    const bf16_t* __restrict__ Qh, const bf16_t* __restrict__ Kh,
    const bf16_t* __restrict__ Vh, bf16_t* __restrict__ AO) {
  __shared__ bf16_t Ks[64 * 128];          // 16 KB, swizzled
  __shared__ bf16_t Vs[128 * 66];          // 16.5 KB, V^T padded
  __shared__ bf16_t Pq[4 * 2 * 16 * 64];   // 16 KB, per-wave P
  const int t = threadIdx.x;
  const int lane = t & 63, wave = t >> 6;
  const int c = lane & 15, g = lane >> 4;

  // grid remap: xcd-grouped heads + complementary qt pairing (id, id+256)
  const int id = blockIdx.x;
  const int xcd = id & 7, j2 = (id >> 3) & 3, qt8 = (id >> 5) & 7, half = id >> 8;
  const int qt = half ? (15 - qt8) : qt8;
  const int hb = xcd * 4 + j2;
  const int h = hb & 15, b = hb >> 4;
  const int kvh = h >> 1;                  // GQA n_rep = 2

  const int qbase = qt * 128 + wave * 32;
  const int qg0 = qbase + c, qg1 = qbase + 16 + c;

  const bf16_t* qp = Qh + (((long)b * NHEAD + h) * SS) * DD;
  bf16x8 qf[2][4];
#pragma unroll
  for (int qc = 0; qc < 2; ++qc)
#pragma unroll
    for (int kb = 0; kb < 4; ++kb)
      qf[qc][kb] = *reinterpret_cast<const bf16x8*>(
          qp + (long)(qbase + qc * 16 + c) * DD + kb * 32 + g * 8);

  const bf16_t* kp = Kh + ((long)b * NKVH + kvh) * SS * DD;
  const bf16_t* vp = Vh + ((long)b * NKVH + kvh) * SS * DD;

  f32x4 o[8][2] = {};
  float mrow[2] = {-1e30f, -1e30f}, lrow[2] = {0.f, 0.f};
  const int srow2 = t >> 4, sc16 = t & 15;
  const int kv_end = qt * 128 + 128;
  const float scale = 0.08838834764831845f;   // 1/sqrt(128)
  const int c7x8 = 8 * (c & 7);
  unsigned short* Vsu = reinterpret_cast<unsigned short*>(Vs);

  for (int kv0 = 0; kv0 < kv_end; kv0 += 64) {
    __syncthreads();
#pragma unroll
    for (int rr = 0; rr < 4; ++rr) {
      const int row = srow2 + rr * 16;
      uint4 kvv = *reinterpret_cast<const uint4*>(kp + (long)(kv0 + row) * DD + sc16 * 8);
      *reinterpret_cast<uint4*>(&Ks[row * 128 + 8 * (sc16 ^ (row & 7))]) = kvv;
      // V^T scatter (verified v1 semantics, stride 66)
      uint4 vvv = *reinterpret_cast<const uint4*>(vp + (long)(kv0 + row) * DD + sc16 * 8);
      unsigned int vw[4] = {vvv.x, vvv.y, vvv.z, vvv.w};
#pragma unroll
      for (int j = 0; j < 4; ++j) {
        Vsu[(sc16 * 8 + 2 * j) * 66 + row]     = (unsigned short)(vw[j] & 0xffffu);
        Vsu[(sc16 * 8 + 2 * j + 1) * 66 + row] = (unsigned short)(vw[j] >> 16);
      }
    }
    __syncthreads();

    if (kv0 <= qbase + 31) {      // wave-uniform: skip fully-masked tiles
      // ---- S^T = K·Q^T ----
      f32x4 s[2][4] = {};
#pragma unroll
      for (int kb = 0; kb < 4; ++kb) {
        bf16x8 kf[4];
#pragma unroll
        for (int kc = 0; kc < 4; ++kc)
          kf[kc] = *reinterpret_cast<const bf16x8*>(
              &Ks[(kc * 16 + c) * 128 + 8 * (((kb << 2) | g) ^ (c & 7))]);
#pragma unroll
        for (int qc = 0; qc < 2; ++qc)
#pragma unroll
          for (int kc = 0; kc < 4; ++kc)
            s[qc][kc] = __builtin_amdgcn_mfma_f32_16x16x32_bf16(
                kf[kc], qf[qc][kb], s[qc][kc], 0, 0, 0);
      }
      // ---- online softmax (per qc), P^T -> per-wave LDS ----
#pragma unroll
      for (int qc = 0; qc < 2; ++qc) {
        const int qg = qc ? qg1 : qg0;
        float sv[16];
#pragma unroll
        for (int i = 0; i < 16; ++i) {
          const int key = kv0 + (i >> 2) * 16 + 4 * g + (i & 3);
          const float x = s[qc][i >> 2][i & 3];
          sv[i] = (key <= qg) ? x * scale : -1e30f;
        }
        float vm = sv[0];
#pragma unroll
        for (int i = 1; i < 16; ++i) vm = fmaxf(vm, sv[i]);
        vm = fmaxf(vm, __shfl_xor(vm, 16));
        vm = fmaxf(vm, __shfl_xor(vm, 32));
        const float mnew = fmaxf(mrow[qc], vm);
        const float alpha = __expf(mrow[qc] - mnew);
        float p[16], ps = 0.f;
#pragma unroll
        for (int i = 0; i < 16; ++i) { p[i] = __expf(sv[i] - mnew); ps += p[i]; }
        ps += __shfl_xor(ps, 16);
        ps += __shfl_xor(ps, 32);
        lrow[qc] = lrow[qc] * alpha + ps;
        mrow[qc] = mnew;
#pragma unroll
        for (int dt = 0; dt < 8; ++dt) o[dt][qc] = o[dt][qc] * alpha;
#pragma unroll
        for (int kc = 0; kc < 4; ++kc) {
          bf16x4 pk;
#pragma unroll
          for (int r = 0; r < 4; ++r) pk[r] = (bf16_t)p[kc * 4 + r];
          *reinterpret_cast<bf16x4*>(
              &Pq[((wave * 2 + qc) * 16 + c) * 64 + ((kc * 16 + 4 * g) ^ c7x8)]) = pk;
        }
      }
      // ---- O^T += V^T · P^T ----
#pragma unroll
      for (int kc2 = 0; kc2 < 2; ++kc2) {
        bf16x8 pf[2];
#pragma unroll
        for (int qc = 0; qc < 2; ++qc)
          pf[qc] = *reinterpret_cast<const bf16x8*>(
              &Pq[((wave * 2 + qc) * 16 + c) * 64 + ((kc2 * 32 + g * 8) ^ c7x8)]);
#pragma unroll
        for (int dt = 0; dt < 8; ++dt) {
          // vf = V^T[dt*16+c][kc2*32 + g*8 .. +8], stride-66 row, 4x b32
          const int eb = (dt * 16 + c) * 66 + kc2 * 32 + g * 8;
          union { uint32_t u[4]; bf16x8 v; } vu;
          const uint32_t* vsrc = reinterpret_cast<const uint32_t*>(&Vs[eb]);
          vu.u[0] = vsrc[0]; vu.u[1] = vsrc[1];
          vu.u[2] = vsrc[2]; vu.u[3] = vsrc[3];
#pragma unroll
          for (int qc = 0; qc < 2; ++qc)
            o[dt][qc] = __builtin_amdgcn_mfma_f32_16x16x32_bf16(
                vu.v, pf[qc], o[dt][qc], 0, 0, 0);
        }
      }
    }
  }
  // ---- epilogue ----
#pragma unroll
  for (int qc = 0; qc < 2; ++qc) {
    const float linv = 1.0f / lrow[qc];
    bf16_t* aop = AO + ((long)(b * SS) + qbase + qc * 16 + c) * (NHEAD * DD) + h * DD;
#pragma unroll
    for (int dt = 0; dt < 8; ++dt) {
      bf16x4 ov;
#pragma unroll
      for (int r = 0; r < 4; ++r) ov[r] = (bf16_t)(o[dt][qc][r] * linv);
      *reinterpret_cast<bf16x4*>(aop + dt * 16 + 4 * g) = ov;
    }
  }
}

// ---------------- launch ----------------
extern "C" void kernel_launch(void* const* d_in, const int* in_sizes, int n_in,
                              void* d_out, int out_size, void* d_ws, size_t ws_size,
                              hipStream_t stream) {
  const float* hidden = (const float*)d_in[0];
  const float* cosb   = (const float*)d_in[1];
  const float* sinb   = (const float*)d_in[2];
  const float* Wq     = (const float*)d_in[3];
  const float* Wk     = (const float*)d_in[4];
  const float* Wv     = (const float*)d_in[5];
  const float* Wo     = (const float*)d_in[6];
  const float* qnw    = (const float*)d_in[7];
  const float* knw    = (const float*)d_in[8];
  float* outp = (float*)d_out;
  char* ws = (char*)d_ws;
  const size_t MB = 1024 * 1024;
  bf16_t* hbf  = (bf16_t*)(ws + 0);
  bf16_t* wqb  = (bf16_t*)(ws + 8 * MB);
  bf16_t* wkb  = (bf16_t*)(ws + 12 * MB);
  bf16_t* wvb  = (bf16_t*)(ws + 14 * MB);
  bf16_t* wob  = (bf16_t*)(ws + 16 * MB);
  bf16_t* qraw = (bf16_t*)(ws + 20 * MB);
  bf16_t* kraw = (bf16_t*)(ws + 36 * MB);
  bf16_t* vraw = (bf16_t*)(ws + 44 * MB);
  bf16_t* qn   = (bf16_t*)(ws + 52 * MB);
  bf16_t* kn   = (bf16_t*)(ws + 68 * MB);
  bf16_t* vn   = (bf16_t*)(ws + 76 * MB);
  bf16_t* ao   = qraw;

  k_cvt<<<2048, 256, 0, stream>>>(hidden, hbf, MM * HH / 4);
  k_cvt<<<1024, 256, 0, stream>>>(Wq, wqb, NHEAD * DD * HH / 4);
  k_cvt<<<512, 256, 0, stream>>>(Wk, wkb, NKVH * DD * HH / 4);
  k_cvt<<<512, 256, 0, stream>>>(Wv, wvb, NKVH * DD * HH / 4);
  k_cvt<<<1024, 256, 0, stream>>>(Wo, wob, HH * NHEAD * DD / 4);

  k_gemm_bt<bf16_t><<<dim3(16, 32), 256, 0, stream>>>(hbf, wqb, qraw, MM, 2048, 1024);
  k_gemm_bt<bf16_t><<<dim3(8, 32), 256, 0, stream>>>(hbf, wkb, kraw, MM, 1024, 1024);
  k_gemm_bt<bf16_t><<<dim3(8, 32), 256, 0, stream>>>(hbf, wvb, vraw, MM, 1024, 1024);

  k_nr<1><<<MM * NHEAD / 4, 256, 0, stream>>>(qraw, qn, qnw, cosb, sinb, NHEAD);
  k_nr<1><<<MM * NKVH / 4, 256, 0, stream>>>(kraw, kn, knw, cosb, sinb, NKVH);
  k_nr<0><<<MM * NKVH / 4, 256, 0, stream>>>(vraw, vn, knw, cosb, sinb, NKVH);

  k_attn<<<dim3(512), 256, 0, stream>>>(qn, kn, vn, ao);

  k_gemm_bt<float><<<dim3(8, 32), 256, 0, stream>>>(ao, wob, outp, MM, 1024, 2048);
}

// Round 7
// 309.285 us; speedup vs baseline: 2.6910x; 1.8650x over previous
//
#include <hip/hip_runtime.h>
#include <hip/hip_bf16.h>
#include <stdint.h>

#define BB 2
#define SS 2048
#define HH 1024
#define NHEAD 16
#define NKVH 8
#define DD 128
#define MM (BB*SS)   // 4096 rows

typedef __bf16 bf16_t;
typedef __bf16 bf16x8 __attribute__((ext_vector_type(8)));
typedef __bf16 bf16x4 __attribute__((ext_vector_type(4)));
typedef float  f32x4  __attribute__((ext_vector_type(4)));

// ---------------- fp32 -> bf16 convert (vectorized, grid-stride) ----------------
__global__ __launch_bounds__(256) void k_cvt(const float* __restrict__ in,
                                             bf16_t* __restrict__ out, int n4) {
  int i = blockIdx.x * 256 + threadIdx.x;
  const int stride = gridDim.x * 256;
  for (; i < n4; i += stride) {
    float4 v = reinterpret_cast<const float4*>(in)[i];
    bf16x4 o;
    o[0] = (bf16_t)v.x; o[1] = (bf16_t)v.y; o[2] = (bf16_t)v.z; o[3] = (bf16_t)v.w;
    reinterpret_cast<bf16x4*>(out)[i] = o;
  }
}

// ---------------- GEMM: C[M,N] = A[M,K] * B[N,K]^T  (bf16 in, CT out) ----------------
// m97 structure: 128x128 tile, BK=64, 4 waves (2x2), global_load_lds width-16
// staging into linear LDS [128][64], 2-barrier K-loop (no swizzle: T2 null at
// 2-phase per m252). ~3 blocks/CU via launch_bounds(256,3) for TLP overlap.
template <typename CT>
__global__ __launch_bounds__(256, 3) void k_gemm_lds(
    const bf16_t* __restrict__ A, const bf16_t* __restrict__ Bm,
    CT* __restrict__ C, int M, int N, int K) {
  __shared__ bf16_t As[128 * 64];   // 16 KB, linear (lane-order contiguous)
  __shared__ bf16_t Bs[128 * 64];   // 16 KB
  const int t = threadIdx.x;
  const int lane = t & 63, wave = t >> 6;
  const int c = lane & 15, g = lane >> 4;
  const int wm = wave >> 1, wn = wave & 1;
  const long m0 = (long)blockIdx.y * 128;
  const long n0 = (long)blockIdx.x * 128;
  const int srow = t >> 3, sc8 = t & 7;   // staging: row = i*32+srow, col8 = sc8

  const bf16_t* Ag = A + (m0 + srow) * K + sc8 * 8;
  const bf16_t* Bg = Bm + (n0 + srow) * K + sc8 * 8;

  f32x4 acc[4][4] = {};
  const int nk = K >> 6;
  for (int kt = 0; kt < nk; ++kt) {
    const long koff = (long)kt * 64;
    __syncthreads();   // previous tile's compute done before overwrite
#pragma unroll
    for (int i = 0; i < 4; ++i) {
      // dest = wave-uniform base + lane*16; elem (i*256+t)*8 -> row i*32+srow, col sc8*8
      __builtin_amdgcn_global_load_lds(
          (const __attribute__((address_space(1))) uint32_t*)(const void*)(Ag + (long)i * 32 * K + koff),
          (__attribute__((address_space(3))) uint32_t*)(void*)(&As[(i * 256 + t) * 8]),
          16, 0, 0);
      __builtin_amdgcn_global_load_lds(
          (const __attribute__((address_space(1))) uint32_t*)(const void*)(Bg + (long)i * 32 * K + koff),
          (__attribute__((address_space(3))) uint32_t*)(void*)(&Bs[(i * 256 + t) * 8]),
          16, 0, 0);
    }
    __syncthreads();   // compiler drains vmcnt(0) before this barrier
#pragma unroll
    for (int kk = 0; kk < 2; ++kk) {
      bf16x8 af[4], bfr[4];
#pragma unroll
      for (int mi = 0; mi < 4; ++mi)
        af[mi] = *reinterpret_cast<const bf16x8*>(
            &As[(wm * 64 + mi * 16 + c) * 64 + kk * 32 + g * 8]);
#pragma unroll
      for (int ni = 0; ni < 4; ++ni)
        bfr[ni] = *reinterpret_cast<const bf16x8*>(
            &Bs[(wn * 64 + ni * 16 + c) * 64 + kk * 32 + g * 8]);
#pragma unroll
      for (int mi = 0; mi < 4; ++mi)
#pragma unroll
        for (int ni = 0; ni < 4; ++ni)
          acc[mi][ni] = __builtin_amdgcn_mfma_f32_16x16x32_bf16(
              af[mi], bfr[ni], acc[mi][ni], 0, 0, 0);
    }
  }
  // C/D layout: col = lane&15, row = (lane>>4)*4 + r
#pragma unroll
  for (int mi = 0; mi < 4; ++mi)
#pragma unroll
    for (int ni = 0; ni < 4; ++ni)
#pragma unroll
      for (int r = 0; r < 4; ++r) {
        long m = m0 + wm * 64 + mi * 16 + 4 * g + r;
        long n = n0 + wn * 64 + ni * 16 + c;
        C[m * N + n] = (CT)acc[mi][ni][r];
      }
}

// ---------------- fused RMSNorm + RoPE + [B,S,h,D]->[B,h,S,D] transpose ----------------
// raw rows have stride rstride (fused QKV output); head h at col offset h*DD.
template <int DO_NR>
__global__ __launch_bounds__(256) void k_nr(
    const bf16_t* __restrict__ raw, bf16_t* __restrict__ outp,
    const float* __restrict__ w, const float* __restrict__ cosb,
    const float* __restrict__ sinb, int nheads, int rstride) {
  const int wid = (blockIdx.x * 256 + threadIdx.x) >> 6;
  const int lane = threadIdx.x & 63;
  const int h = wid % nheads;
  const int bs = wid / nheads;           // b*S + s
  const int b = bs / SS, s = bs - b * SS;
  const bf16_t* rp = raw + (long)bs * rstride + h * DD;
  float x0 = (float)rp[lane];
  float x1 = (float)rp[lane + 64];
  bf16_t o0, o1;
  if (DO_NR) {
    float ssq = x0 * x0 + x1 * x1;
#pragma unroll
    for (int m = 1; m < 64; m <<= 1) ssq += __shfl_xor(ssq, m);
    const float rs = rsqrtf(ssq * (1.0f / DD) + 1e-6f);
    const float xn0 = x0 * rs * w[lane];
    const float xn1 = x1 * rs * w[lane + 64];
    const float cc = cosb[(long)bs * DD + lane];
    const float sn = sinb[(long)bs * DD + lane];
    o0 = (bf16_t)(xn0 * cc - xn1 * sn);
    o1 = (bf16_t)(xn1 * cc + xn0 * sn);
  } else {
    o0 = (bf16_t)x0; o1 = (bf16_t)x1;
  }
  bf16_t* op = outp + (((long)b * nheads + h) * SS + s) * DD;
  op[lane] = o0;
  op[lane + 64] = o1;
}

// ---------------- causal GQA flash attention v3 (verified r6) ----------------
__global__ __launch_bounds__(256, 2) void k_attn(
    const bf16_t* __restrict__ Qh, const bf16_t* __restrict__ Kh,
    const bf16_t* __restrict__ Vh, bf16_t* __restrict__ AO) {
  __shared__ bf16_t Ks[64 * 128];          // 16 KB, swizzled
  __shared__ bf16_t Vs[128 * 66];          // 16.5 KB, V^T padded
  __shared__ bf16_t Pq[4 * 2 * 16 * 64];   // 16 KB, per-wave P
  const int t = threadIdx.x;
  const int lane = t & 63, wave = t >> 6;
  const int c = lane & 15, g = lane >> 4;

  // grid remap: xcd-grouped heads + complementary qt pairing (id, id+256)
  const int id = blockIdx.x;
  const int xcd = id & 7, j2 = (id >> 3) & 3, qt8 = (id >> 5) & 7, half = id >> 8;
  const int qt = half ? (15 - qt8) : qt8;
  const int hb = xcd * 4 + j2;
  const int h = hb & 15, b = hb >> 4;
  const int kvh = h >> 1;                  // GQA n_rep = 2

  const int qbase = qt * 128 + wave * 32;
  const int qg0 = qbase + c, qg1 = qbase + 16 + c;

  const bf16_t* qp = Qh + (((long)b * NHEAD + h) * SS) * DD;
  bf16x8 qf[2][4];
#pragma unroll
  for (int qc = 0; qc < 2; ++qc)
#pragma unroll
    for (int kb = 0; kb < 4; ++kb)
      qf[qc][kb] = *reinterpret_cast<const bf16x8*>(
          qp + (long)(qbase + qc * 16 + c) * DD + kb * 32 + g * 8);

  const bf16_t* kp = Kh + ((long)b * NKVH + kvh) * SS * DD;
  const bf16_t* vp = Vh + ((long)b * NKVH + kvh) * SS * DD;

  f32x4 o[8][2] = {};
  float mrow[2] = {-1e30f, -1e30f}, lrow[2] = {0.f, 0.f};
  const int srow2 = t >> 4, sc16 = t & 15;
  const int kv_end = qt * 128 + 128;
  const float scale = 0.08838834764831845f;   // 1/sqrt(128)
  const int c7x8 = 8 * (c & 7);
  unsigned short* Vsu = reinterpret_cast<unsigned short*>(Vs);

  for (int kv0 = 0; kv0 < kv_end; kv0 += 64) {
    __syncthreads();
#pragma unroll
    for (int rr = 0; rr < 4; ++rr) {
      const int row = srow2 + rr * 16;
      uint4 kvv = *reinterpret_cast<const uint4*>(kp + (long)(kv0 + row) * DD + sc16 * 8);
      *reinterpret_cast<uint4*>(&Ks[row * 128 + 8 * (sc16 ^ (row & 7))]) = kvv;
      uint4 vvv = *reinterpret_cast<const uint4*>(vp + (long)(kv0 + row) * DD + sc16 * 8);
      unsigned int vw[4] = {vvv.x, vvv.y, vvv.z, vvv.w};
#pragma unroll
      for (int j = 0; j < 4; ++j) {
        Vsu[(sc16 * 8 + 2 * j) * 66 + row]     = (unsigned short)(vw[j] & 0xffffu);
        Vsu[(sc16 * 8 + 2 * j + 1) * 66 + row] = (unsigned short)(vw[j] >> 16);
      }
    }
    __syncthreads();

    if (kv0 <= qbase + 31) {      // wave-uniform: skip fully-masked tiles
      // ---- S^T = K·Q^T ----
      f32x4 s[2][4] = {};
#pragma unroll
      for (int kb = 0; kb < 4; ++kb) {
        bf16x8 kf[4];
#pragma unroll
        for (int kc = 0; kc < 4; ++kc)
          kf[kc] = *reinterpret_cast<const bf16x8*>(
              &Ks[(kc * 16 + c) * 128 + 8 * (((kb << 2) | g) ^ (c & 7))]);
#pragma unroll
        for (int qc = 0; qc < 2; ++qc)
#pragma unroll
          for (int kc = 0; kc < 4; ++kc)
            s[qc][kc] = __builtin_amdgcn_mfma_f32_16x16x32_bf16(
                kf[kc], qf[qc][kb], s[qc][kc], 0, 0, 0);
      }
      // ---- online softmax (per qc), P^T -> per-wave LDS ----
#pragma unroll
      for (int qc = 0; qc < 2; ++qc) {
        const int qg = qc ? qg1 : qg0;
        float sv[16];
#pragma unroll
        for (int i = 0; i < 16; ++i) {
          const int key = kv0 + (i >> 2) * 16 + 4 * g + (i & 3);
          const float x = s[qc][i >> 2][i & 3];
          sv[i] = (key <= qg) ? x * scale : -1e30f;
        }
        float vm = sv[0];
#pragma unroll
        for (int i = 1; i < 16; ++i) vm = fmaxf(vm, sv[i]);
        vm = fmaxf(vm, __shfl_xor(vm, 16));
        vm = fmaxf(vm, __shfl_xor(vm, 32));
        const float mnew = fmaxf(mrow[qc], vm);
        const float alpha = __expf(mrow[qc] - mnew);
        float p[16], ps = 0.f;
#pragma unroll
        for (int i = 0; i < 16; ++i) { p[i] = __expf(sv[i] - mnew); ps += p[i]; }
        ps += __shfl_xor(ps, 16);
        ps += __shfl_xor(ps, 32);
        lrow[qc] = lrow[qc] * alpha + ps;
        mrow[qc] = mnew;
#pragma unroll
        for (int dt = 0; dt < 8; ++dt) o[dt][qc] = o[dt][qc] * alpha;
#pragma unroll
        for (int kc = 0; kc < 4; ++kc) {
          bf16x4 pk;
#pragma unroll
          for (int r = 0; r < 4; ++r) pk[r] = (bf16_t)p[kc * 4 + r];
          *reinterpret_cast<bf16x4*>(
              &Pq[((wave * 2 + qc) * 16 + c) * 64 + ((kc * 16 + 4 * g) ^ c7x8)]) = pk;
        }
      }
      // ---- O^T += V^T · P^T ----
#pragma unroll
      for (int kc2 = 0; kc2 < 2; ++kc2) {
        bf16x8 pf[2];
#pragma unroll
        for (int qc = 0; qc < 2; ++qc)
          pf[qc] = *reinterpret_cast<const bf16x8*>(
              &Pq[((wave * 2 + qc) * 16 + c) * 64 + ((kc2 * 32 + g * 8) ^ c7x8)]);
#pragma unroll
        for (int dt = 0; dt < 8; ++dt) {
          const int eb = (dt * 16 + c) * 66 + kc2 * 32 + g * 8;
          union { uint32_t u[4]; bf16x8 v; } vu;
          const uint32_t* vsrc = reinterpret_cast<const uint32_t*>(&Vs[eb]);
          vu.u[0] = vsrc[0]; vu.u[1] = vsrc[1];
          vu.u[2] = vsrc[2]; vu.u[3] = vsrc[3];
#pragma unroll
          for (int qc = 0; qc < 2; ++qc)
            o[dt][qc] = __builtin_amdgcn_mfma_f32_16x16x32_bf16(
                vu.v, pf[qc], o[dt][qc], 0, 0, 0);
        }
      }
    }
  }
  // ---- epilogue ----
#pragma unroll
  for (int qc = 0; qc < 2; ++qc) {
    const float linv = 1.0f / lrow[qc];
    bf16_t* aop = AO + ((long)(b * SS) + qbase + qc * 16 + c) * (NHEAD * DD) + h * DD;
#pragma unroll
    for (int dt = 0; dt < 8; ++dt) {
      bf16x4 ov;
#pragma unroll
      for (int r = 0; r < 4; ++r) ov[r] = (bf16_t)(o[dt][qc][r] * linv);
      *reinterpret_cast<bf16x4*>(aop + dt * 16 + 4 * g) = ov;
    }
  }
}

// ---------------- launch ----------------
extern "C" void kernel_launch(void* const* d_in, const int* in_sizes, int n_in,
                              void* d_out, int out_size, void* d_ws, size_t ws_size,
                              hipStream_t stream) {
  const float* hidden = (const float*)d_in[0];
  const float* cosb   = (const float*)d_in[1];
  const float* sinb   = (const float*)d_in[2];
  const float* Wq     = (const float*)d_in[3];
  const float* Wk     = (const float*)d_in[4];
  const float* Wv     = (const float*)d_in[5];
  const float* Wo     = (const float*)d_in[6];
  const float* qnw    = (const float*)d_in[7];
  const float* knw    = (const float*)d_in[8];
  float* outp = (float*)d_out;
  char* ws = (char*)d_ws;
  const size_t MB = 1024 * 1024;
  bf16_t* hbf   = (bf16_t*)(ws + 0);        //  8 MB  hidden bf16 [4096][1024]
  bf16_t* wqkv  = (bf16_t*)(ws + 8 * MB);   //  8 MB  [Wq;Wk;Wv] as [4096][1024]
  bf16_t* wob   = (bf16_t*)(ws + 16 * MB);  //  4 MB
  bf16_t* qkvr  = (bf16_t*)(ws + 20 * MB);  // 32 MB  [4096][4096] fused QKV out
  bf16_t* qn    = (bf16_t*)(ws + 52 * MB);  // 16 MB  [B,NH,S,D]
  bf16_t* kn    = (bf16_t*)(ws + 68 * MB);  //  8 MB  [B,NKV,S,D]
  bf16_t* vn    = (bf16_t*)(ws + 76 * MB);  //  8 MB  [B,NKV,S,D]   (total 84 MB)
  bf16_t* ao    = qkvr;                     // reuse (16 MB needed)

  k_cvt<<<2048, 256, 0, stream>>>(hidden, hbf, MM * HH / 4);
  k_cvt<<<1024, 256, 0, stream>>>(Wq, wqkv, 2048 * HH / 4);
  k_cvt<<<512, 256, 0, stream>>>(Wk, wqkv + 2048 * HH, 1024 * HH / 4);
  k_cvt<<<512, 256, 0, stream>>>(Wv, wqkv + 3072 * HH, 1024 * HH / 4);
  k_cvt<<<1024, 256, 0, stream>>>(Wo, wob, HH * NHEAD * DD / 4);

  // fused QKV projection: C[4096][4096] = hbf[4096][1024] x wqkv^T
  k_gemm_lds<bf16_t><<<dim3(32, 32), 256, 0, stream>>>(hbf, wqkv, qkvr, MM, 4096, 1024);

  k_nr<1><<<MM * NHEAD / 4, 256, 0, stream>>>(qkvr, qn, qnw, cosb, sinb, NHEAD, 4096);
  k_nr<1><<<MM * NKVH / 4, 256, 0, stream>>>(qkvr + 2048, kn, knw, cosb, sinb, NKVH, 4096);
  k_nr<0><<<MM * NKVH / 4, 256, 0, stream>>>(qkvr + 3072, vn, knw, cosb, sinb, NKVH, 4096);

  k_attn<<<dim3(512), 256, 0, stream>>>(qn, kn, vn, ao);

  // output projection (fp32 out)
  k_gemm_lds<float><<<dim3(8, 32), 256, 0, stream>>>(ao, wob, outp, MM, 1024, 2048);
}